// Round 3
// baseline (8707.280 us; speedup 1.0000x reference)
//
#include <hip/hip_runtime.h>

typedef unsigned short u16;
typedef __attribute__((ext_vector_type(8))) short short8;
typedef __attribute__((ext_vector_type(4))) float f32x4;

__device__ __forceinline__ float b2f(u16 h) {
  union { unsigned int u; float f; } v; v.u = ((unsigned int)h) << 16; return v.f;
}
__device__ __forceinline__ u16 f2b(float f) {
  union { float f; unsigned int u; } v; v.f = f;
  return (u16)((v.u + 0x7fffu + ((v.u >> 16) & 1u)) >> 16);
}

// async global->LDS, 16B per lane; dst must be wave-base + lane*16 (m97 pattern)
__device__ __forceinline__ void gload16(const u16* g, u16* l) {
  __builtin_amdgcn_global_load_lds(
      (const __attribute__((address_space(1))) void*)g,
      (__attribute__((address_space(3))) void*)l, 16, 0, 0);
}

#define SENC 1025
#define SPENC 1032
#define NBE 129
#define SDEC 1024
#define NBD 128
#define BATCH 32
#define MENC (BATCH * SPENC)  /* 33024 */
#define MDEC (BATCH * SDEC)   /* 32768 */

// ---------- beacon ----------
__global__ void beacon_k(float* out) { if (threadIdx.x == 0) out[0] = 1000.0f; }

// ---------- weight transpose + bf16 convert: WT[n][k] = bf16(W[k][n]) ----------
__global__ __launch_bounds__(256) void tr_k(const float* __restrict__ W, u16* __restrict__ WT, int K, int N)
{
  __shared__ float sm[32][33];
  int k0 = blockIdx.x * 32, n0 = blockIdx.y * 32;
  const float* Wz = W + (size_t)blockIdx.z * K * N;
  u16* WTz = WT + (size_t)blockIdx.z * K * N;
  int r = threadIdx.x >> 3, c0 = (threadIdx.x & 7) * 4;
  float4 v = *(const float4*)&Wz[(size_t)(k0 + r) * N + n0 + c0];
  sm[r][c0] = v.x; sm[r][c0 + 1] = v.y; sm[r][c0 + 2] = v.z; sm[r][c0 + 3] = v.w;
  __syncthreads();
  ushort4 u;
  u.x = f2b(sm[c0][r]); u.y = f2b(sm[c0 + 1][r]); u.z = f2b(sm[c0 + 2][r]); u.w = f2b(sm[c0 + 3][r]);
  *(ushort4*)&WTz[(size_t)(n0 + r) * K + k0 + c0] = u;
}

// ---------- embed: h fp32 + hb bf16 ----------
__global__ __launch_bounds__(256) void embed_k(const float* __restrict__ x, const float* __restrict__ Wd,
    const float* __restrict__ bd, const float* __restrict__ emb, float* __restrict__ h, u16* __restrict__ hb)
{
  size_t gid = (size_t)blockIdx.x * 256 + threadIdx.x;  // MENC*512
  int dd = (int)(gid & 511);
  size_t rs = gid >> 9;
  int s = (int)(rs % SPENC);
  int b = (int)(rs / SPENC);
  float v;
  if (s == 0) {
    v = emb[dd];
  } else if (s < SENC) {
    float acc = bd[dd];
    const float* xr = x + ((size_t)b * 1024 + (s - 1)) * 16;
    #pragma unroll
    for (int j = 0; j < 16; ++j) acc += xr[j] * Wd[j * 512 + dd];
    v = acc + emb[(size_t)s * 512 + dd];
  } else {
    v = 0.f;
  }
  h[gid] = v;
  hb[gid] = f2b(v);
}

// ---------- MFMA bf16 GEMM, triple-buffered depth-3 pipeline, counted vmcnt ----------
// C[M,N] = A[M,Ktot](bf16) @ WT[N,Ktot]^T(bf16) + bias (+R)(ReLU opt)
// ATOMIC: split-K over blockIdx.z; epilogue does unsafeAtomicAdd into C; bias by z==0 only.
// LDS chunk (16B = 8 bf16): logical k-chunk c of row r stored at slot r*4 + (c ^ ((r>>1)&3))
// K-loop: 3 LDS buffers, loads issued 2 tiles ahead; per-iter: vmcnt(4) [tile t landed,
// tile t+1 still in flight] -> raw s_barrier -> issue tile t+2 -> ds_read frags -> MFMA.
// Requires nt >= 2 (all call sites have Kc >= 256).
template<typename TC, bool RELU, bool RESID, bool ATOMIC>
__global__ __launch_bounds__(256) void mgemm_k(const u16* __restrict__ A, const u16* __restrict__ WT,
    const float* __restrict__ bias, const float* __restrict__ R, TC* __restrict__ C,
    int M, int N, int Kc, int lda, int ldb)
{
  __shared__ __align__(16) u16 sA[3][128 * 32];
  __shared__ __align__(16) u16 sB[3][128 * 32];
  int t = threadIdx.x;
  int n0 = blockIdx.x * 128, m0 = blockIdx.y * 128;
  int koff = blockIdx.z * Kc;
  int lane = t & 63, wave = t >> 6;
  int wm = (wave >> 1) * 64, wn = (wave & 1) * 64;
  int quad = lane >> 4, l15 = lane & 15;

  // staging: issue j in {0,1}: LDS chunk Lc = wave*128 + j*64 + lane (lane-contiguous per wave)
  int r0 = wave * 32 + (lane >> 2);   // row for issue 0
  int r1 = r0 + 16;                    // row for issue 1
  int sc = lane & 3;                   // stored chunk slot
  int c0 = sc ^ ((r0 >> 1) & 3);       // logical k-chunk fetched into slot
  int c1 = sc ^ ((r1 >> 1) & 3);
  int ra0 = m0 + r0; ra0 = ra0 < M ? ra0 : M - 1;
  int ra1 = m0 + r1; ra1 = ra1 < M ? ra1 : M - 1;
  const u16* gA0 = A + (size_t)ra0 * lda + koff + c0 * 8;
  const u16* gA1 = A + (size_t)ra1 * lda + koff + c1 * 8;
  const u16* gB0 = WT + (size_t)(n0 + r0) * ldb + koff + c0 * 8;
  const u16* gB1 = WT + (size_t)(n0 + r1) * ldb + koff + c1 * 8;
  u16* lA0 = &sA[0][(wave * 128 + lane) * 8];
  u16* lA1 = &sA[0][(wave * 128 + 64 + lane) * 8];
  u16* lB0 = &sB[0][(wave * 128 + lane) * 8];
  u16* lB1 = &sB[0][(wave * 128 + 64 + lane) * 8];

  f32x4 acc[4][4];
  #pragma unroll
  for (int i = 0; i < 4; ++i)
    #pragma unroll
    for (int j = 0; j < 4; ++j) acc[i][j] = (f32x4){0.f, 0.f, 0.f, 0.f};

  const int nt = Kc >> 5;
  // prologue: stage tile 0 -> buf 0, tile 1 -> buf 1 (8 loads in flight)
  gload16(gA0, lA0); gload16(gA1, lA1); gload16(gB0, lB0); gload16(gB1, lB1);
  gload16(gA0 + 32, lA0 + 4096); gload16(gA1 + 32, lA1 + 4096);
  gload16(gB0 + 32, lB0 + 4096); gload16(gB1 + 32, lB1 + 4096);

  int cur = 0;
  for (int tt = 0; tt < nt; ++tt) {
    // wait for tile tt's 4 loads (leave tile tt+1's 4 in flight), then sync
    if (tt < nt - 1) {
      asm volatile("s_waitcnt vmcnt(4)" ::: "memory");
    } else {
      asm volatile("s_waitcnt vmcnt(0)" ::: "memory");
    }
    __builtin_amdgcn_s_barrier();
    if (tt + 2 < nt) {
      int k0 = (tt + 2) << 5;
      int nb = tt + 2; nb -= (nb / 3) * 3;   // (tt+2) % 3
      int off = nb * 4096;
      gload16(gA0 + k0, lA0 + off);
      gload16(gA1 + k0, lA1 + off);
      gload16(gB0 + k0, lB0 + off);
      gload16(gB1 + k0, lB1 + off);
    }
    short8 af[4], bf[4];
    #pragma unroll
    for (int i = 0; i < 4; ++i) {
      int ra = wm + i * 16 + l15;
      af[i] = *(const short8*)&sA[cur][ra * 32 + (quad ^ ((ra >> 1) & 3)) * 8];
    }
    #pragma unroll
    for (int j = 0; j < 4; ++j) {
      int rb = wn + j * 16 + l15;
      bf[j] = *(const short8*)&sB[cur][rb * 32 + (quad ^ ((rb >> 1) & 3)) * 8];
    }
    #pragma unroll
    for (int i = 0; i < 4; ++i)
      #pragma unroll
      for (int j = 0; j < 4; ++j)
        acc[i][j] = __builtin_amdgcn_mfma_f32_16x16x32_bf16(af[i], bf[j], acc[i][j], 0, 0, 0);
    cur = (cur == 2) ? 0 : cur + 1;
  }

  // epilogue: D row = quad*4+reg (m), col = lane&15 (n)  [m89-verified]
  #pragma unroll
  for (int i = 0; i < 4; ++i) {
    int mBase = m0 + wm + i * 16 + quad * 4;
    #pragma unroll
    for (int r = 0; r < 4; ++r) {
      int m = mBase + r;
      if (m < M) {
        #pragma unroll
        for (int j = 0; j < 4; ++j) {
          int n = n0 + wn + j * 16 + l15;
          if constexpr (ATOMIC) {
            float v = acc[i][j][r];
            if (blockIdx.z == 0) v += bias[n];
            unsafeAtomicAdd(&((float*)C)[(size_t)m * N + n], v);
          } else {
            float v = acc[i][j][r] + bias[n];
            if (RESID) v += R[(size_t)m * N + n];
            if (RELU) v = fmaxf(v, 0.f);
            if constexpr (sizeof(TC) == 2) ((u16*)C)[(size_t)m * N + n] = f2b(v);
            else ((float*)C)[(size_t)m * N + n] = v;
          }
        }
      }
    }
  }
}

// ---------- in-place LayerNorm, also emits bf16 shadow ----------
__global__ __launch_bounds__(256) void ln_k(float* h, u16* __restrict__ hb,
    const float* __restrict__ g, const float* __restrict__ bb)
{
  __shared__ float rs[256], rq[256];
  float* p = h + (size_t)blockIdx.x * 512;
  u16* pb = hb + (size_t)blockIdx.x * 512;
  int t = threadIdx.x;
  float v0 = p[t], v1 = p[t + 256];
  rs[t] = v0 + v1; rq[t] = v0 * v0 + v1 * v1;
  __syncthreads();
  for (int o = 128; o > 0; o >>= 1) {
    if (t < o) { rs[t] += rs[t + o]; rq[t] += rq[t + o]; }
    __syncthreads();
  }
  float mean = rs[0] * (1.f / 512.f);
  float var = fmaxf(rq[0] * (1.f / 512.f) - mean * mean, 0.f);
  float rinv = rsqrtf(var + 1e-5f);
  float o0 = (v0 - mean) * rinv * g[t] + bb[t];
  float o1 = (v1 - mean) * rinv * g[t + 256] + bb[t + 256];
  p[t] = o0; p[t + 256] = o1;
  pb[t] = f2b(o0); pb[t + 256] = f2b(o1);
}

// ---------- sparse block attention (bf16 qkv in, bf16 av out) ----------
__global__ __launch_bounds__(128) void attnb_k(const u16* __restrict__ qkv, u16* __restrict__ av,
    const int* __restrict__ rnd, int S, int Sp, int nb)
{
  __shared__ float sS[8][80];
  __shared__ float sQ[8][64];
  __shared__ int sJB[10], sVD[10];
  int t = threadIdx.x;
  int n = blockIdx.x % nb;
  int r1 = blockIdx.x / nb;
  int hh = r1 & 7, b = r1 >> 3;
  const u16* base = qkv + (size_t)b * Sp * 1536;

  if (t < 10) {
    int jb, vd;
    if (t < 2) { jb = t; vd = 1; }
    else if (t < 7) {
      int w = n + t - 4;
      vd = (w >= 0 && w < nb) ? 1 : 0;
      jb = w < 0 ? 0 : (w > nb - 1 ? nb - 1 : w);
    } else { jb = rnd[n * 3 + t - 7]; vd = 1; }
    sJB[t] = jb; sVD[t] = vd;
  }
  {
    int idx4 = t * 4;
    int qi = idx4 >> 6, c = idx4 & 63;
    ushort4 u = *(const ushort4*)(base + (size_t)(n * 8 + qi) * 1536 + hh * 64 + c);
    sQ[qi][c] = b2f(u.x); sQ[qi][c + 1] = b2f(u.y); sQ[qi][c + 2] = b2f(u.z); sQ[qi][c + 3] = b2f(u.w);
  }
  __syncthreads();
  if (t < 80) {
    int kb = t >> 3, kj = t & 7;
    int tok = sJB[kb] * 8 + kj;
    const u16* kp = base + (size_t)tok * 1536 + 512 + hh * 64;
    bool ok = sVD[kb] && (tok < S);
    float d8[8];
    #pragma unroll
    for (int qi = 0; qi < 8; ++qi) d8[qi] = 0.f;
    for (int c = 0; c < 64; c += 4) {
      ushort4 u = *(const ushort4*)(kp + c);
      float k0 = b2f(u.x), k1 = b2f(u.y), k2 = b2f(u.z), k3 = b2f(u.w);
      #pragma unroll
      for (int qi = 0; qi < 8; ++qi)
        d8[qi] += sQ[qi][c] * k0 + sQ[qi][c + 1] * k1 + sQ[qi][c + 2] * k2 + sQ[qi][c + 3] * k3;
    }
    #pragma unroll
    for (int qi = 0; qi < 8; ++qi) sS[qi][t] = ok ? d8[qi] * 0.125f : -1.0e9f;
  }
  __syncthreads();
  // wave-parallel softmax: 8 lanes per row
  if (t < 64) {
    int r = t >> 3, c = t & 7;
    float mx = -3.0e38f;
    for (int k = c; k < 80; k += 8) mx = fmaxf(mx, sS[r][k]);
    #pragma unroll
    for (int off = 1; off < 8; off <<= 1) mx = fmaxf(mx, __shfl_xor(mx, off));
    float sum = 0.f;
    for (int k = c; k < 80; k += 8) { float e = __expf(sS[r][k] - mx); sS[r][k] = e; sum += e; }
    #pragma unroll
    for (int off = 1; off < 8; off <<= 1) sum += __shfl_xor(sum, off);
    float inv = 1.f / sum;
    for (int k = c; k < 80; k += 8) sS[r][k] *= inv;
  }
  __syncthreads();
  {
    int qi = t >> 4, dd = (t & 15) << 2;
    float o0 = 0, o1 = 0, o2 = 0, o3 = 0;
    for (int k = 0; k < 80; ++k) {
      float pp = sS[qi][k];
      int tok = sJB[k >> 3] * 8 + (k & 7);
      ushort4 u = *(const ushort4*)(base + (size_t)tok * 1536 + 1024 + hh * 64 + dd);
      o0 += pp * b2f(u.x); o1 += pp * b2f(u.y); o2 += pp * b2f(u.z); o3 += pp * b2f(u.w);
    }
    ushort4 u; u.x = f2b(o0); u.y = f2b(o1); u.z = f2b(o2); u.w = f2b(o3);
    *(ushort4*)(av + ((size_t)b * Sp + n * 8 + qi) * 512 + hh * 64 + dd) = u;
  }
}

// ---------- VAE head ----------
__global__ __launch_bounds__(512) void head_k(const float* __restrict__ h,
    const float* __restrict__ Wm, const float* __restrict__ bm,
    const float* __restrict__ Wlv, const float* __restrict__ blv,
    const float* __restrict__ eps, float* __restrict__ z, float* out_elbo)
{
  __shared__ float red[512];
  int t = threadIdx.x;
  int b = t >> 4, i = t & 15;
  const float* p = h + (size_t)b * SPENC * 512;
  float am = bm[i], al = blv[i];
  for (int c = 0; c < 512; ++c) {
    float pv = p[c];
    am += pv * Wm[c * 16 + i];
    al += pv * Wlv[c * 16 + i];
  }
  z[t] = am + eps[t] * expf(0.5f * al);
  red[t] = -0.5f * (1.f + al - am * am - expf(al));
  __syncthreads();
  for (int o = 256; o > 0; o >>= 1) { if (t < o) red[t] += red[t + o]; __syncthreads(); }
  if (t == 0) out_elbo[0] = red[0] * (1.f / 32.f);
}

// ---------- seq ----------
__global__ __launch_bounds__(256) void seq_k(const float* __restrict__ z, const float* __restrict__ We,
    const float* __restrict__ be, float* __restrict__ seq)
{
  int gid = blockIdx.x * 256 + threadIdx.x;
  int b = gid >> 11, c = gid & 2047;
  float acc = be[c];
  #pragma unroll
  for (int i = 0; i < 16; ++i) acc += z[b * 16 + i] * We[i * 2048 + c];
  seq[gid] = acc;
}

// ---------- decoder init: h fp32 + hb bf16 ----------
__global__ __launch_bounds__(256) void decinit_k(const float* __restrict__ seq, const float* __restrict__ Wc,
    const float* __restrict__ bc, const float* __restrict__ emb, float* __restrict__ h, u16* __restrict__ hb)
{
  size_t gid = (size_t)blockIdx.x * 256 + threadIdx.x;
  int dd = (int)(gid & 511);
  size_t rs = gid >> 9;
  int s = (int)(rs & 1023);
  int b = (int)(rs >> 10);
  float v = seq[b * 2048 + s] * Wc[dd] + seq[b * 2048 + 1024 + s] * Wc[512 + dd]
          + bc[dd] + emb[(size_t)s * 512 + dd];
  h[gid] = v;
  hb[gid] = f2b(v);
}

// ---------- final ----------
__global__ __launch_bounds__(256) void final_k(const float* __restrict__ h, const float* __restrict__ Ws,
    const float* __restrict__ bs, float* __restrict__ out)
{
  int gid = blockIdx.x * 256 + threadIdx.x;
  int nn = gid & 15;
  int rs = gid >> 4;
  const float* p = h + (size_t)rs * 512;
  float acc = bs[nn];
  for (int c = 0; c < 512; ++c) acc += p[c] * Ws[c * 16 + nn];
  out[gid] = acc;
}

extern "C" void kernel_launch(void* const* d_in, const int* in_sizes, int n_in,
                              void* d_out, int out_size, void* d_ws, size_t ws_size,
                              hipStream_t stream) {
  float* out = (float*)d_out;
  (void)out_size; (void)ws_size;

  static const int EXP_DICT[30] = {
    524288, 512, 524800, 524288, 8192, 512, 7864320, 15360, 2621440, 5120,
    5120, 5120, 10485760, 20480, 10485760, 5120, 5120, 5120, 8192, 16,
    8192, 16, 32768, 2048, 1024, 512, 8192, 16, 387, 384 };
  bool dict_ok = (n_in == 30);
  if (dict_ok) for (int i = 0; i < 30; ++i) if (in_sizes[i] != EXP_DICT[i]) { dict_ok = false; break; }
  if (!dict_ok) { beacon_k<<<1, 64, 0, stream>>>(out); return; }

  const float* x      = (const float*)d_in[0];
  const float* eps    = (const float*)d_in[1];
  const float* emb_in = (const float*)d_in[2];
  const float* emb_out= (const float*)d_in[3];
  const float* W_data = (const float*)d_in[4];
  const float* b_data = (const float*)d_in[5];
  const float* Wqkv   = (const float*)d_in[6];
  const float* bqkv   = (const float*)d_in[7];
  const float* Wo     = (const float*)d_in[8];
  const float* bo     = (const float*)d_in[9];
  const float* ln1g   = (const float*)d_in[10];
  const float* ln1b   = (const float*)d_in[11];
  const float* W1     = (const float*)d_in[12];
  const float* b1     = (const float*)d_in[13];
  const float* W2     = (const float*)d_in[14];
  const float* b2     = (const float*)d_in[15];
  const float* ln2g   = (const float*)d_in[16];
  const float* ln2b   = (const float*)d_in[17];
  const float* Wm     = (const float*)d_in[18];
  const float* bm     = (const float*)d_in[19];
  const float* Wlv    = (const float*)d_in[20];
  const float* blv    = (const float*)d_in[21];
  const float* Wexp   = (const float*)d_in[22];
  const float* bexp   = (const float*)d_in[23];
  const float* Wconv  = (const float*)d_in[24];
  const float* bconv  = (const float*)d_in[25];
  const float* Wseq   = (const float*)d_in[26];
  const float* bseq   = (const float*)d_in[27];
  const int* rand_enc = (const int*)d_in[28];
  const int* rand_dec = (const int*)d_in[29];

  // ---- workspace carve (~194.5 MB; proven-safe envelope 203 MB) ----
  char* ws = (char*)d_ws;
  float* h     = (float*)ws;
  u16*   hb    = (u16*)(ws + 67633152);
  u16*   WTqkv = (u16*)(ws + 101449728);
  u16*   WTo   = (u16*)(ws + 117178368);
  u16*   WT1l  = (u16*)(ws + 122421248);
  u16*   WT2l  = (u16*)(ws + 124518400);
  u16*   qkvb  = (u16*)(ws + 126615552);
  u16*   avb   = (u16*)(ws + 126615552 + 50724864);
  u16*   ffnb  = (u16*)(ws + 126615552);             // union with qkvb+avb
  float* seqb  = (float*)(ws + 194248704);
  float* z     = (float*)(ws + 194510848);

  // ---- persistent weight transpose+convert (qkv, o for all 10 layers) ----
  tr_k<<<dim3(512 / 32, 1536 / 32, 10), 256, 0, stream>>>(Wqkv, WTqkv, 512, 1536);
  tr_k<<<dim3(512 / 32, 512 / 32, 10), 256, 0, stream>>>(Wo, WTo, 512, 512);

  // ===== encoder: M=33024; attention path in 2 chunks of 16 batches (Mc=16512) =====
  {
    const int M = MENC;
    embed_k<<<(M * 512) / 256, 256, 0, stream>>>(x, W_data, b_data, emb_in, h, hb);
    for (int i = 0; i < 5; ++i) {
      for (int bc = 0; bc < 2; ++bc) {
        size_t roff = (size_t)bc * 16 * SPENC * 512;
        const int Mc = 16 * SPENC;  // 16512
        const int ty = 129;         // 16512/128
        mgemm_k<u16, false, false, false><<<dim3(1536 / 128, ty, 1), 256, 0, stream>>>(
            hb + roff, WTqkv + (size_t)i * 512 * 1536, bqkv + (size_t)i * 1536, nullptr, qkvb, Mc, 1536, 512, 512, 512);
        attnb_k<<<16 * 8 * NBE, 128, 0, stream>>>(qkvb, avb, rand_enc, SENC, SPENC, NBE);
        // Wo: split-K=2, atomic into h (h pre-holds residual)
        mgemm_k<float, false, false, true><<<dim3(512 / 128, ty, 2), 256, 0, stream>>>(
            avb, WTo + (size_t)i * 512 * 512, bo + (size_t)i * 512, nullptr, h + roff, Mc, 512, 256, 512, 512);
      }
      ln_k<<<M, 256, 0, stream>>>(h, hb, ln1g + (size_t)i * 512, ln1b + (size_t)i * 512);
      // per-layer FFN weight transposes (WT1l/WT2l)
      tr_k<<<dim3(512 / 32, 2048 / 32, 1), 256, 0, stream>>>(W1 + (size_t)i * 512 * 2048, WT1l, 512, 2048);
      tr_k<<<dim3(2048 / 32, 512 / 32, 1), 256, 0, stream>>>(W2 + (size_t)i * 2048 * 512, WT2l, 2048, 512);
      for (int off = 0; off < M; off += 16512) {
        const int Mc = 16512;  // 33024 = 2 * 16512 exactly
        const int ty = 129;
        mgemm_k<u16, true, false, false><<<dim3(2048 / 128, ty, 1), 256, 0, stream>>>(
            hb + (size_t)off * 512, WT1l, b1 + (size_t)i * 2048, nullptr, ffnb, Mc, 2048, 512, 512, 512);
        // W2: split-K=2 (Kc=1024), atomic into h (h pre-holds post-ln1 residual)
        mgemm_k<float, false, false, true><<<dim3(512 / 128, ty, 2), 256, 0, stream>>>(
            ffnb, WT2l, b2 + (size_t)i * 512, nullptr, h + (size_t)off * 512, Mc, 512, 1024, 2048, 2048);
      }
      ln_k<<<M, 256, 0, stream>>>(h, hb, ln2g + (size_t)i * 512, ln2b + (size_t)i * 512);
    }
  }

  // ===== VAE head =====
  head_k<<<1, 512, 0, stream>>>(h, Wm, bm, Wlv, blv, eps, z, out + 524288);
  seq_k<<<256, 256, 0, stream>>>(z, Wexp, bexp, seqb);
  decinit_k<<<(MDEC * 512) / 256, 256, 0, stream>>>(seqb, Wconv, bconv, emb_out, h, hb);

  // ===== decoder: M=32768; attention path in 2 chunks of 16 batches (Mc=16384) =====
  {
    const int M = MDEC;
    for (int i = 5; i < 10; ++i) {
      for (int bc = 0; bc < 2; ++bc) {
        size_t roff = (size_t)bc * 16 * SDEC * 512;
        const int Mc = 16 * SDEC;  // 16384
        const int ty = 128;
        mgemm_k<u16, false, false, false><<<dim3(1536 / 128, ty, 1), 256, 0, stream>>>(
            hb + roff, WTqkv + (size_t)i * 512 * 1536, bqkv + (size_t)i * 1536, nullptr, qkvb, Mc, 1536, 512, 512, 512);
        attnb_k<<<16 * 8 * NBD, 128, 0, stream>>>(qkvb, avb, rand_dec, SDEC, SDEC, NBD);
        mgemm_k<float, false, false, true><<<dim3(512 / 128, ty, 2), 256, 0, stream>>>(
            avb, WTo + (size_t)i * 512 * 512, bo + (size_t)i * 512, nullptr, h + roff, Mc, 512, 256, 512, 512);
      }
      ln_k<<<M, 256, 0, stream>>>(h, hb, ln1g + (size_t)i * 512, ln1b + (size_t)i * 512);
      tr_k<<<dim3(512 / 32, 2048 / 32, 1), 256, 0, stream>>>(W1 + (size_t)i * 512 * 2048, WT1l, 512, 2048);
      tr_k<<<dim3(2048 / 32, 512 / 32, 1), 256, 0, stream>>>(W2 + (size_t)i * 2048 * 512, WT2l, 2048, 512);
      for (int off = 0; off < M; off += 16384) {
        const int Mc = 16384;
        const int ty = 128;
        mgemm_k<u16, true, false, false><<<dim3(2048 / 128, ty, 1), 256, 0, stream>>>(
            hb + (size_t)off * 512, WT1l, b1 + (size_t)i * 2048, nullptr, ffnb, Mc, 2048, 512, 512, 512);
        mgemm_k<float, false, false, true><<<dim3(512 / 128, ty, 2), 256, 0, stream>>>(
            ffnb, WT2l, b2 + (size_t)i * 512, nullptr, h + (size_t)off * 512, Mc, 512, 1024, 2048, 2048);
      }
      ln_k<<<M, 256, 0, stream>>>(h, hb, ln2g + (size_t)i * 512, ln2b + (size_t)i * 512);
    }
  }

  // ===== output =====
  final_k<<<524288 / 256, 256, 0, stream>>>(h, Wseq, bseq, out);
}

// Round 4
// 7174.516 us; speedup vs baseline: 1.2136x; 1.2136x over previous
//
#include <hip/hip_runtime.h>

typedef unsigned short u16;
typedef __attribute__((ext_vector_type(8))) short short8;
typedef __attribute__((ext_vector_type(4))) float f32x4;

__device__ __forceinline__ float b2f(u16 h) {
  union { unsigned int u; float f; } v; v.u = ((unsigned int)h) << 16; return v.f;
}
__device__ __forceinline__ u16 f2b(float f) {
  union { float f; unsigned int u; } v; v.f = f;
  return (u16)((v.u + 0x7fffu + ((v.u >> 16) & 1u)) >> 16);
}

// async global->LDS, 16B per lane; dst must be wave-base + lane*16 (m97 pattern)
__device__ __forceinline__ void gload16(const u16* g, u16* l) {
  __builtin_amdgcn_global_load_lds(
      (const __attribute__((address_space(1))) void*)g,
      (__attribute__((address_space(3))) void*)l, 16, 0, 0);
}

#define SENC 1025
#define SPENC 1032
#define NBE 129
#define SDEC 1024
#define NBD 128
#define BATCH 32
#define MENC (BATCH * SPENC)  /* 33024 */
#define MDEC (BATCH * SDEC)   /* 32768 */

// ---------- beacon ----------
__global__ void beacon_k(float* out) { if (threadIdx.x == 0) out[0] = 1000.0f; }

// ---------- weight transpose + bf16 convert: WT[n][k] = bf16(W[k][n]) ----------
__global__ __launch_bounds__(256) void tr_k(const float* __restrict__ W, u16* __restrict__ WT, int K, int N)
{
  __shared__ float sm[32][33];
  int k0 = blockIdx.x * 32, n0 = blockIdx.y * 32;
  const float* Wz = W + (size_t)blockIdx.z * K * N;
  u16* WTz = WT + (size_t)blockIdx.z * K * N;
  int r = threadIdx.x >> 3, c0 = (threadIdx.x & 7) * 4;
  float4 v = *(const float4*)&Wz[(size_t)(k0 + r) * N + n0 + c0];
  sm[r][c0] = v.x; sm[r][c0 + 1] = v.y; sm[r][c0 + 2] = v.z; sm[r][c0 + 3] = v.w;
  __syncthreads();
  ushort4 u;
  u.x = f2b(sm[c0][r]); u.y = f2b(sm[c0 + 1][r]); u.z = f2b(sm[c0 + 2][r]); u.w = f2b(sm[c0 + 3][r]);
  *(ushort4*)&WTz[(size_t)(n0 + r) * K + k0 + c0] = u;
}

// ---------- embed: h fp32 + hb bf16 ----------
__global__ __launch_bounds__(256) void embed_k(const float* __restrict__ x, const float* __restrict__ Wd,
    const float* __restrict__ bd, const float* __restrict__ emb, float* __restrict__ h, u16* __restrict__ hb)
{
  size_t gid = (size_t)blockIdx.x * 256 + threadIdx.x;  // MENC*512
  int dd = (int)(gid & 511);
  size_t rs = gid >> 9;
  int s = (int)(rs % SPENC);
  int b = (int)(rs / SPENC);
  float v;
  if (s == 0) {
    v = emb[dd];
  } else if (s < SENC) {
    float acc = bd[dd];
    const float* xr = x + ((size_t)b * 1024 + (s - 1)) * 16;
    #pragma unroll
    for (int j = 0; j < 16; ++j) acc += xr[j] * Wd[j * 512 + dd];
    v = acc + emb[(size_t)s * 512 + dd];
  } else {
    v = 0.f;
  }
  h[gid] = v;
  hb[gid] = f2b(v);
}

// ---------- MFMA bf16 GEMM, triple-buffered depth-3 pipeline, counted vmcnt ----------
// C[M,N] = A[M,Ktot](bf16) @ WT[N,Ktot]^T(bf16) + bias (+R)(ReLU opt)
// ATOMIC: split-K over blockIdx.z; epilogue does unsafeAtomicAdd into C; bias by z==0 only.
// LDS chunk (16B = 8 bf16): logical k-chunk c of row r stored at slot r*4 + (c ^ ((r>>1)&3))
template<typename TC, bool RELU, bool RESID, bool ATOMIC>
__global__ __launch_bounds__(256) void mgemm_k(const u16* __restrict__ A, const u16* __restrict__ WT,
    const float* __restrict__ bias, const float* __restrict__ R, TC* __restrict__ C,
    int M, int N, int Kc, int lda, int ldb)
{
  __shared__ __align__(16) u16 sA[3][128 * 32];
  __shared__ __align__(16) u16 sB[3][128 * 32];
  int t = threadIdx.x;
  int n0 = blockIdx.x * 128, m0 = blockIdx.y * 128;
  int koff = blockIdx.z * Kc;
  int lane = t & 63, wave = t >> 6;
  int wm = (wave >> 1) * 64, wn = (wave & 1) * 64;
  int quad = lane >> 4, l15 = lane & 15;

  int r0 = wave * 32 + (lane >> 2);
  int r1 = r0 + 16;
  int sc = lane & 3;
  int c0 = sc ^ ((r0 >> 1) & 3);
  int c1 = sc ^ ((r1 >> 1) & 3);
  int ra0 = m0 + r0; ra0 = ra0 < M ? ra0 : M - 1;
  int ra1 = m0 + r1; ra1 = ra1 < M ? ra1 : M - 1;
  const u16* gA0 = A + (size_t)ra0 * lda + koff + c0 * 8;
  const u16* gA1 = A + (size_t)ra1 * lda + koff + c1 * 8;
  const u16* gB0 = WT + (size_t)(n0 + r0) * ldb + koff + c0 * 8;
  const u16* gB1 = WT + (size_t)(n0 + r1) * ldb + koff + c1 * 8;
  u16* lA0 = &sA[0][(wave * 128 + lane) * 8];
  u16* lA1 = &sA[0][(wave * 128 + 64 + lane) * 8];
  u16* lB0 = &sB[0][(wave * 128 + lane) * 8];
  u16* lB1 = &sB[0][(wave * 128 + 64 + lane) * 8];

  f32x4 acc[4][4];
  #pragma unroll
  for (int i = 0; i < 4; ++i)
    #pragma unroll
    for (int j = 0; j < 4; ++j) acc[i][j] = (f32x4){0.f, 0.f, 0.f, 0.f};

  const int nt = Kc >> 5;
  gload16(gA0, lA0); gload16(gA1, lA1); gload16(gB0, lB0); gload16(gB1, lB1);
  gload16(gA0 + 32, lA0 + 4096); gload16(gA1 + 32, lA1 + 4096);
  gload16(gB0 + 32, lB0 + 4096); gload16(gB1 + 32, lB1 + 4096);

  int cur = 0;
  for (int tt = 0; tt < nt; ++tt) {
    if (tt < nt - 1) {
      asm volatile("s_waitcnt vmcnt(4)" ::: "memory");
    } else {
      asm volatile("s_waitcnt vmcnt(0)" ::: "memory");
    }
    __builtin_amdgcn_s_barrier();
    if (tt + 2 < nt) {
      int k0 = (tt + 2) << 5;
      int nb = tt + 2; nb -= (nb / 3) * 3;
      int off = nb * 4096;
      gload16(gA0 + k0, lA0 + off);
      gload16(gA1 + k0, lA1 + off);
      gload16(gB0 + k0, lB0 + off);
      gload16(gB1 + k0, lB1 + off);
    }
    short8 af[4], bf[4];
    #pragma unroll
    for (int i = 0; i < 4; ++i) {
      int ra = wm + i * 16 + l15;
      af[i] = *(const short8*)&sA[cur][ra * 32 + (quad ^ ((ra >> 1) & 3)) * 8];
    }
    #pragma unroll
    for (int j = 0; j < 4; ++j) {
      int rb = wn + j * 16 + l15;
      bf[j] = *(const short8*)&sB[cur][rb * 32 + (quad ^ ((rb >> 1) & 3)) * 8];
    }
    #pragma unroll
    for (int i = 0; i < 4; ++i)
      #pragma unroll
      for (int j = 0; j < 4; ++j)
        acc[i][j] = __builtin_amdgcn_mfma_f32_16x16x32_bf16(af[i], bf[j], acc[i][j], 0, 0, 0);
    cur = (cur == 2) ? 0 : cur + 1;
  }

  #pragma unroll
  for (int i = 0; i < 4; ++i) {
    int mBase = m0 + wm + i * 16 + quad * 4;
    #pragma unroll
    for (int r = 0; r < 4; ++r) {
      int m = mBase + r;
      if (m < M) {
        #pragma unroll
        for (int j = 0; j < 4; ++j) {
          int n = n0 + wn + j * 16 + l15;
          if constexpr (ATOMIC) {
            float v = acc[i][j][r];
            if (blockIdx.z == 0) v += bias[n];
            unsafeAtomicAdd(&((float*)C)[(size_t)m * N + n], v);
          } else {
            float v = acc[i][j][r] + bias[n];
            if (RESID) v += R[(size_t)m * N + n];
            if (RELU) v = fmaxf(v, 0.f);
            if constexpr (sizeof(TC) == 2) ((u16*)C)[(size_t)m * N + n] = f2b(v);
            else ((float*)C)[(size_t)m * N + n] = v;
          }
        }
      }
    }
  }
}

// ---------- in-place LayerNorm, also emits bf16 shadow ----------
__global__ __launch_bounds__(256) void ln_k(float* h, u16* __restrict__ hb,
    const float* __restrict__ g, const float* __restrict__ bb)
{
  __shared__ float rs[256], rq[256];
  float* p = h + (size_t)blockIdx.x * 512;
  u16* pb = hb + (size_t)blockIdx.x * 512;
  int t = threadIdx.x;
  float v0 = p[t], v1 = p[t + 256];
  rs[t] = v0 + v1; rq[t] = v0 * v0 + v1 * v1;
  __syncthreads();
  for (int o = 128; o > 0; o >>= 1) {
    if (t < o) { rs[t] += rs[t + o]; rq[t] += rq[t + o]; }
    __syncthreads();
  }
  float mean = rs[0] * (1.f / 512.f);
  float var = fmaxf(rq[0] * (1.f / 512.f) - mean * mean, 0.f);
  float rinv = rsqrtf(var + 1e-5f);
  float o0 = (v0 - mean) * rinv * g[t] + bb[t];
  float o1 = (v1 - mean) * rinv * g[t + 256] + bb[t + 256];
  p[t] = o0; p[t + 256] = o1;
  pb[t] = f2b(o0); pb[t + 256] = f2b(o1);
}

// ---------- sparse block attention, MFMA version: one wave per (b, h, n) ----------
// QK^T: A = Q (rows 0..7 valid of 16), B = K (token-major = native B layout), 5 tiles x 2 K-steps.
// Softmax in registers (C rows = quad*4+r, cols = l15), unnormalized; 1/sum in epilogue.
// PV: A = P (LDS, bf16), B = V^T (LDS, transposed at stage time), 3 K-steps x 4 d-tiles.
// Strides padded to 104 u16 (16B-aligned); P/V^T token cols 80..95 zeroed (K=96 padding).
__global__ __launch_bounds__(64) void attnm_k(const u16* __restrict__ qkv, u16* __restrict__ av,
    const int* __restrict__ rnd, int S, int Sp, int nb)
{
  __shared__ __align__(16) u16 Vt[64 * 104];
  __shared__ __align__(16) u16 Pl[16 * 104];
  __shared__ int sJB[10], sVD[10];
  int t = threadIdx.x;
  int n = blockIdx.x % nb;
  int r1 = blockIdx.x / nb;
  int hh = r1 & 7, b = r1 >> 3;
  const u16* base = qkv + (size_t)b * Sp * 1536;
  int l15 = t & 15, quad = t >> 4;

  if (t < 10) {
    int jb, vd;
    if (t < 2) { jb = t; vd = 1; }
    else if (t < 7) {
      int w = n + t - 4;
      vd = (w >= 0 && w < nb) ? 1 : 0;
      jb = w < 0 ? 0 : (w > nb - 1 ? nb - 1 : w);
    } else { jb = rnd[n * 3 + t - 7]; vd = 1; }
    sJB[t] = jb; sVD[t] = vd;
  }
  {
    f32x4 zz = {0.f, 0.f, 0.f, 0.f};
    *(f32x4*)&Vt[t * 104 + 80] = zz;
    *(f32x4*)&Vt[t * 104 + 88] = zz;
    if (t < 16) {
      *(f32x4*)&Pl[t * 104 + 80] = zz;
      *(f32x4*)&Pl[t * 104 + 88] = zz;
    }
  }
  __syncthreads();

  // Q fragment: A[row = l15&7][k chunk = quad*8 within each 32-dim step]
  short8 aq0, aq1;
  {
    const u16* qp = base + (size_t)(n * 8 + (l15 & 7)) * 1536 + hh * 64 + quad * 8;
    aq0 = *(const short8*)qp;
    aq1 = *(const short8*)(qp + 32);
  }

  // QK^T: 5 token-tiles of 16; B fragment loaded straight from gathered K rows
  f32x4 s[5];
  float okm[5];
  #pragma unroll
  for (int tile = 0; tile < 5; ++tile) {
    int kb = tile * 2 + (l15 >> 3);
    int tok = sJB[kb] * 8 + (l15 & 7);
    okm[tile] = (sVD[kb] && tok < S) ? 0.f : -3.0e38f;
    const u16* kp = base + (size_t)tok * 1536 + 512 + hh * 64 + quad * 8;
    short8 k0 = *(const short8*)kp;
    short8 k1 = *(const short8*)(kp + 32);
    f32x4 c = {0.f, 0.f, 0.f, 0.f};
    c = __builtin_amdgcn_mfma_f32_16x16x32_bf16(aq0, k0, c, 0, 0, 0);
    c = __builtin_amdgcn_mfma_f32_16x16x32_bf16(aq1, k1, c, 0, 0, 0);
    s[tile] = c;
  }

  // V loads: lane t = dim, 8 tokens per gathered block (coalesced 2B across lanes)
  u16 vreg[80];
  #pragma unroll
  for (int vt = 0; vt < 10; ++vt) {
    const u16* vp = base + (size_t)(sJB[vt] * 8) * 1536 + 1024 + hh * 64 + t;
    #pragma unroll
    for (int j = 0; j < 8; ++j) vreg[vt * 8 + j] = vp[(size_t)j * 1536];
  }

  // softmax (rows = quad*4+r, cols = l15 across 16-lane groups); unnormalized
  f32x4 mx = {-3.0e38f, -3.0e38f, -3.0e38f, -3.0e38f};
  #pragma unroll
  for (int tile = 0; tile < 5; ++tile) {
    #pragma unroll
    for (int r = 0; r < 4; ++r) {
      float v = s[tile][r] * 0.125f + okm[tile];
      s[tile][r] = v;
      mx[r] = fmaxf(mx[r], v);
    }
  }
  #pragma unroll
  for (int off = 1; off < 16; off <<= 1) {
    #pragma unroll
    for (int r = 0; r < 4; ++r) mx[r] = fmaxf(mx[r], __shfl_xor(mx[r], off));
  }
  f32x4 sm = {0.f, 0.f, 0.f, 0.f};
  #pragma unroll
  for (int tile = 0; tile < 5; ++tile) {
    #pragma unroll
    for (int r = 0; r < 4; ++r) {
      float e = __expf(s[tile][r] - mx[r]);
      s[tile][r] = e;
      sm[r] += e;
    }
  }
  #pragma unroll
  for (int off = 1; off < 16; off <<= 1) {
    #pragma unroll
    for (int r = 0; r < 4; ++r) sm[r] += __shfl_xor(sm[r], off);
  }

  // write P (bf16, unnormalized) to LDS
  #pragma unroll
  for (int tile = 0; tile < 5; ++tile)
    #pragma unroll
    for (int r = 0; r < 4; ++r)
      Pl[(quad * 4 + r) * 104 + tile * 16 + l15] = f2b(s[tile][r]);

  // write V^T rows (contiguous 16B per lane-row)
  #pragma unroll
  for (int vt = 0; vt < 10; ++vt) {
    short8 w;
    #pragma unroll
    for (int j = 0; j < 8; ++j) ((u16*)&w)[j] = (short)vreg[vt * 8 + j];
    *(short8*)&Vt[t * 104 + vt * 8] = w;
  }
  __syncthreads();

  // PV: C[q][d] = sum_tok P[q][tok] * Vt[d][tok]
  f32x4 o[4];
  #pragma unroll
  for (int dn = 0; dn < 4; ++dn) o[dn] = (f32x4){0.f, 0.f, 0.f, 0.f};
  #pragma unroll
  for (int ks = 0; ks < 3; ++ks) {
    short8 ap = *(const short8*)&Pl[l15 * 104 + ks * 32 + quad * 8];
    #pragma unroll
    for (int dn = 0; dn < 4; ++dn) {
      short8 bv = *(const short8*)&Vt[(dn * 16 + l15) * 104 + ks * 32 + quad * 8];
      o[dn] = __builtin_amdgcn_mfma_f32_16x16x32_bf16(ap, bv, o[dn], 0, 0, 0);
    }
  }

  // epilogue: rows quad*4+r (valid 0..7 -> quads 0,1), cols dn*16+l15; scale by 1/sum
  if (quad < 2) {
    #pragma unroll
    for (int r = 0; r < 4; ++r) {
      int qi = quad * 4 + r;
      float inv = 1.f / sm[r];
      u16* op = av + ((size_t)b * Sp + n * 8 + qi) * 512 + hh * 64 + l15;
      #pragma unroll
      for (int dn = 0; dn < 4; ++dn)
        op[dn * 16] = f2b(o[dn][r] * inv);
    }
  }
}

// ---------- VAE head ----------
__global__ __launch_bounds__(512) void head_k(const float* __restrict__ h,
    const float* __restrict__ Wm, const float* __restrict__ bm,
    const float* __restrict__ Wlv, const float* __restrict__ blv,
    const float* __restrict__ eps, float* __restrict__ z, float* out_elbo)
{
  __shared__ float red[512];
  int t = threadIdx.x;
  int b = t >> 4, i = t & 15;
  const float* p = h + (size_t)b * SPENC * 512;
  float am = bm[i], al = blv[i];
  for (int c = 0; c < 512; ++c) {
    float pv = p[c];
    am += pv * Wm[c * 16 + i];
    al += pv * Wlv[c * 16 + i];
  }
  z[t] = am + eps[t] * expf(0.5f * al);
  red[t] = -0.5f * (1.f + al - am * am - expf(al));
  __syncthreads();
  for (int o = 256; o > 0; o >>= 1) { if (t < o) red[t] += red[t + o]; __syncthreads(); }
  if (t == 0) out_elbo[0] = red[0] * (1.f / 32.f);
}

// ---------- seq ----------
__global__ __launch_bounds__(256) void seq_k(const float* __restrict__ z, const float* __restrict__ We,
    const float* __restrict__ be, float* __restrict__ seq)
{
  int gid = blockIdx.x * 256 + threadIdx.x;
  int b = gid >> 11, c = gid & 2047;
  float acc = be[c];
  #pragma unroll
  for (int i = 0; i < 16; ++i) acc += z[b * 16 + i] * We[i * 2048 + c];
  seq[gid] = acc;
}

// ---------- decoder init: h fp32 + hb bf16 ----------
__global__ __launch_bounds__(256) void decinit_k(const float* __restrict__ seq, const float* __restrict__ Wc,
    const float* __restrict__ bc, const float* __restrict__ emb, float* __restrict__ h, u16* __restrict__ hb)
{
  size_t gid = (size_t)blockIdx.x * 256 + threadIdx.x;
  int dd = (int)(gid & 511);
  size_t rs = gid >> 9;
  int s = (int)(rs & 1023);
  int b = (int)(rs >> 10);
  float v = seq[b * 2048 + s] * Wc[dd] + seq[b * 2048 + 1024 + s] * Wc[512 + dd]
          + bc[dd] + emb[(size_t)s * 512 + dd];
  h[gid] = v;
  hb[gid] = f2b(v);
}

// ---------- final ----------
__global__ __launch_bounds__(256) void final_k(const float* __restrict__ h, const float* __restrict__ Ws,
    const float* __restrict__ bs, float* __restrict__ out)
{
  int gid = blockIdx.x * 256 + threadIdx.x;
  int nn = gid & 15;
  int rs = gid >> 4;
  const float* p = h + (size_t)rs * 512;
  float acc = bs[nn];
  for (int c = 0; c < 512; ++c) acc += p[c] * Ws[c * 16 + nn];
  out[gid] = acc;
}

extern "C" void kernel_launch(void* const* d_in, const int* in_sizes, int n_in,
                              void* d_out, int out_size, void* d_ws, size_t ws_size,
                              hipStream_t stream) {
  float* out = (float*)d_out;
  (void)out_size; (void)ws_size;

  static const int EXP_DICT[30] = {
    524288, 512, 524800, 524288, 8192, 512, 7864320, 15360, 2621440, 5120,
    5120, 5120, 10485760, 20480, 10485760, 5120, 5120, 5120, 8192, 16,
    8192, 16, 32768, 2048, 1024, 512, 8192, 16, 387, 384 };
  bool dict_ok = (n_in == 30);
  if (dict_ok) for (int i = 0; i < 30; ++i) if (in_sizes[i] != EXP_DICT[i]) { dict_ok = false; break; }
  if (!dict_ok) { beacon_k<<<1, 64, 0, stream>>>(out); return; }

  const float* x      = (const float*)d_in[0];
  const float* eps    = (const float*)d_in[1];
  const float* emb_in = (const float*)d_in[2];
  const float* emb_out= (const float*)d_in[3];
  const float* W_data = (const float*)d_in[4];
  const float* b_data = (const float*)d_in[5];
  const float* Wqkv   = (const float*)d_in[6];
  const float* bqkv   = (const float*)d_in[7];
  const float* Wo     = (const float*)d_in[8];
  const float* bo     = (const float*)d_in[9];
  const float* ln1g   = (const float*)d_in[10];
  const float* ln1b   = (const float*)d_in[11];
  const float* W1     = (const float*)d_in[12];
  const float* b1     = (const float*)d_in[13];
  const float* W2     = (const float*)d_in[14];
  const float* b2     = (const float*)d_in[15];
  const float* ln2g   = (const float*)d_in[16];
  const float* ln2b   = (const float*)d_in[17];
  const float* Wm     = (const float*)d_in[18];
  const float* bm     = (const float*)d_in[19];
  const float* Wlv    = (const float*)d_in[20];
  const float* blv    = (const float*)d_in[21];
  const float* Wexp   = (const float*)d_in[22];
  const float* bexp   = (const float*)d_in[23];
  const float* Wconv  = (const float*)d_in[24];
  const float* bconv  = (const float*)d_in[25];
  const float* Wseq   = (const float*)d_in[26];
  const float* bseq   = (const float*)d_in[27];
  const int* rand_enc = (const int*)d_in[28];
  const int* rand_dec = (const int*)d_in[29];

  // ---- workspace carve (~194.5 MB; proven-safe envelope 203 MB) ----
  char* ws = (char*)d_ws;
  float* h     = (float*)ws;
  u16*   hb    = (u16*)(ws + 67633152);
  u16*   WTqkv = (u16*)(ws + 101449728);
  u16*   WTo   = (u16*)(ws + 117178368);
  u16*   WT1l  = (u16*)(ws + 122421248);
  u16*   WT2l  = (u16*)(ws + 124518400);
  u16*   qkvb  = (u16*)(ws + 126615552);
  u16*   avb   = (u16*)(ws + 126615552 + 50724864);
  u16*   ffnb  = (u16*)(ws + 126615552);             // union with qkvb+avb
  float* seqb  = (float*)(ws + 194248704);
  float* z     = (float*)(ws + 194510848);

  // ---- persistent weight transpose+convert (qkv, o for all 10 layers) ----
  tr_k<<<dim3(512 / 32, 1536 / 32, 10), 256, 0, stream>>>(Wqkv, WTqkv, 512, 1536);
  tr_k<<<dim3(512 / 32, 512 / 32, 10), 256, 0, stream>>>(Wo, WTo, 512, 512);

  // ===== encoder: M=33024; attention path in 2 chunks of 16 batches (Mc=16512) =====
  {
    const int M = MENC;
    embed_k<<<(M * 512) / 256, 256, 0, stream>>>(x, W_data, b_data, emb_in, h, hb);
    for (int i = 0; i < 5; ++i) {
      for (int bc = 0; bc < 2; ++bc) {
        size_t roff = (size_t)bc * 16 * SPENC * 512;
        const int Mc = 16 * SPENC;  // 16512
        const int ty = 129;         // 16512/128
        mgemm_k<u16, false, false, false><<<dim3(1536 / 128, ty, 1), 256, 0, stream>>>(
            hb + roff, WTqkv + (size_t)i * 512 * 1536, bqkv + (size_t)i * 1536, nullptr, qkvb, Mc, 1536, 512, 512, 512);
        attnm_k<<<16 * 8 * NBE, 64, 0, stream>>>(qkvb, avb, rand_enc, SENC, SPENC, NBE);
        // Wo: split-K=2, atomic into h (h pre-holds residual)
        mgemm_k<float, false, false, true><<<dim3(512 / 128, ty, 2), 256, 0, stream>>>(
            avb, WTo + (size_t)i * 512 * 512, bo + (size_t)i * 512, nullptr, h + roff, Mc, 512, 256, 512, 512);
      }
      ln_k<<<M, 256, 0, stream>>>(h, hb, ln1g + (size_t)i * 512, ln1b + (size_t)i * 512);
      // per-layer FFN weight transposes (WT1l/WT2l)
      tr_k<<<dim3(512 / 32, 2048 / 32, 1), 256, 0, stream>>>(W1 + (size_t)i * 512 * 2048, WT1l, 512, 2048);
      tr_k<<<dim3(2048 / 32, 512 / 32, 1), 256, 0, stream>>>(W2 + (size_t)i * 2048 * 512, WT2l, 2048, 512);
      for (int off = 0; off < M; off += 16512) {
        const int Mc = 16512;  // 33024 = 2 * 16512 exactly
        const int ty = 129;
        mgemm_k<u16, true, false, false><<<dim3(2048 / 128, ty, 1), 256, 0, stream>>>(
            hb + (size_t)off * 512, WT1l, b1 + (size_t)i * 2048, nullptr, ffnb, Mc, 2048, 512, 512, 512);
        // W2: split-K=2 (Kc=1024), atomic into h (h pre-holds post-ln1 residual)
        mgemm_k<float, false, false, true><<<dim3(512 / 128, ty, 2), 256, 0, stream>>>(
            ffnb, WT2l, b2 + (size_t)i * 512, nullptr, h + (size_t)off * 512, Mc, 512, 1024, 2048, 2048);
      }
      ln_k<<<M, 256, 0, stream>>>(h, hb, ln2g + (size_t)i * 512, ln2b + (size_t)i * 512);
    }
  }

  // ===== VAE head =====
  head_k<<<1, 512, 0, stream>>>(h, Wm, bm, Wlv, blv, eps, z, out + 524288);
  seq_k<<<256, 256, 0, stream>>>(z, Wexp, bexp, seqb);
  decinit_k<<<(MDEC * 512) / 256, 256, 0, stream>>>(seqb, Wconv, bconv, emb_out, h, hb);

  // ===== decoder: M=32768; attention path in 2 chunks of 16 batches (Mc=16384) =====
  {
    const int M = MDEC;
    for (int i = 5; i < 10; ++i) {
      for (int bc = 0; bc < 2; ++bc) {
        size_t roff = (size_t)bc * 16 * SDEC * 512;
        const int Mc = 16 * SDEC;  // 16384
        const int ty = 128;
        mgemm_k<u16, false, false, false><<<dim3(1536 / 128, ty, 1), 256, 0, stream>>>(
            hb + roff, WTqkv + (size_t)i * 512 * 1536, bqkv + (size_t)i * 1536, nullptr, qkvb, Mc, 1536, 512, 512, 512);
        attnm_k<<<16 * 8 * NBD, 64, 0, stream>>>(qkvb, avb, rand_dec, SDEC, SDEC, NBD);
        mgemm_k<float, false, false, true><<<dim3(512 / 128, ty, 2), 256, 0, stream>>>(
            avb, WTo + (size_t)i * 512 * 512, bo + (size_t)i * 512, nullptr, h + roff, Mc, 512, 256, 512, 512);
      }
      ln_k<<<M, 256, 0, stream>>>(h, hb, ln1g + (size_t)i * 512, ln1b + (size_t)i * 512);
      tr_k<<<dim3(512 / 32, 2048 / 32, 1), 256, 0, stream>>>(W1 + (size_t)i * 512 * 2048, WT1l, 512, 2048);
      tr_k<<<dim3(2048 / 32, 512 / 32, 1), 256, 0, stream>>>(W2 + (size_t)i * 2048 * 512, WT2l, 2048, 512);
      for (int off = 0; off < M; off += 16384) {
        const int Mc = 16384;
        const int ty = 128;
        mgemm_k<u16, true, false, false><<<dim3(2048 / 128, ty, 1), 256, 0, stream>>>(
            hb + (size_t)off * 512, WT1l, b1 + (size_t)i * 2048, nullptr, ffnb, Mc, 2048, 512, 512, 512);
        mgemm_k<float, false, false, true><<<dim3(512 / 128, ty, 2), 256, 0, stream>>>(
            ffnb, WT2l, b2 + (size_t)i * 512, nullptr, h + (size_t)off * 512, Mc, 512, 1024, 2048, 2048);
      }
      ln_k<<<M, 256, 0, stream>>>(h, hb, ln2g + (size_t)i * 512, ln2b + (size_t)i * 512);
    }
  }

  // ===== output =====
  final_k<<<524288 / 256, 256, 0, stream>>>(h, Wseq, bseq, out);
}

// Round 5
// 6830.066 us; speedup vs baseline: 1.2748x; 1.0504x over previous
//
#include <hip/hip_runtime.h>

typedef unsigned short u16;
typedef __attribute__((ext_vector_type(8))) short short8;
typedef __attribute__((ext_vector_type(4))) float f32x4;

__device__ __forceinline__ float b2f(u16 h) {
  union { unsigned int u; float f; } v; v.u = ((unsigned int)h) << 16; return v.f;
}
__device__ __forceinline__ u16 f2b(float f) {
  union { float f; unsigned int u; } v; v.f = f;
  return (u16)((v.u + 0x7fffu + ((v.u >> 16) & 1u)) >> 16);
}

// async global->LDS, 16B per lane; dst must be wave-base + lane*16 (m97 pattern)
__device__ __forceinline__ void gload16(const u16* g, u16* l) {
  __builtin_amdgcn_global_load_lds(
      (const __attribute__((address_space(1))) void*)g,
      (__attribute__((address_space(3))) void*)l, 16, 0, 0);
}

#define SENC 1025
#define SPENC 1032
#define NBE 129
#define SDEC 1024
#define NBD 128
#define BATCH 32
#define MENC (BATCH * SPENC)  /* 33024 */
#define MDEC (BATCH * SDEC)   /* 32768 */

// ---------- beacon ----------
__global__ void beacon_k(float* out) { if (threadIdx.x == 0) out[0] = 1000.0f; }

// ---------- weight transpose + bf16 convert: WT[n][k] = bf16(W[k][n]) ----------
__global__ __launch_bounds__(256) void tr_k(const float* __restrict__ W, u16* __restrict__ WT, int K, int N)
{
  __shared__ float sm[32][33];
  int k0 = blockIdx.x * 32, n0 = blockIdx.y * 32;
  const float* Wz = W + (size_t)blockIdx.z * K * N;
  u16* WTz = WT + (size_t)blockIdx.z * K * N;
  int r = threadIdx.x >> 3, c0 = (threadIdx.x & 7) * 4;
  float4 v = *(const float4*)&Wz[(size_t)(k0 + r) * N + n0 + c0];
  sm[r][c0] = v.x; sm[r][c0 + 1] = v.y; sm[r][c0 + 2] = v.z; sm[r][c0 + 3] = v.w;
  __syncthreads();
  ushort4 u;
  u.x = f2b(sm[c0][r]); u.y = f2b(sm[c0 + 1][r]); u.z = f2b(sm[c0 + 2][r]); u.w = f2b(sm[c0 + 3][r]);
  *(ushort4*)&WTz[(size_t)(n0 + r) * K + k0 + c0] = u;
}

// ---------- embed: h fp32 + hb bf16 ----------
__global__ __launch_bounds__(256) void embed_k(const float* __restrict__ x, const float* __restrict__ Wd,
    const float* __restrict__ bd, const float* __restrict__ emb, float* __restrict__ h, u16* __restrict__ hb)
{
  size_t gid = (size_t)blockIdx.x * 256 + threadIdx.x;  // MENC*512
  int dd = (int)(gid & 511);
  size_t rs = gid >> 9;
  int s = (int)(rs % SPENC);
  int b = (int)(rs / SPENC);
  float v;
  if (s == 0) {
    v = emb[dd];
  } else if (s < SENC) {
    float acc = bd[dd];
    const float* xr = x + ((size_t)b * 1024 + (s - 1)) * 16;
    #pragma unroll
    for (int j = 0; j < 16; ++j) acc += xr[j] * Wd[j * 512 + dd];
    v = acc + emb[(size_t)s * 512 + dd];
  } else {
    v = 0.f;
  }
  h[gid] = v;
  hb[gid] = f2b(v);
}

// ---------- MFMA bf16 GEMM, 128x256 tile, 512 threads, 2-phase dbuf + XCD swizzle ----------
// C[M,N] = A[M,Ktot](bf16) @ WT[N,Ktot]^T(bf16) + bias (+R)(ReLU opt)
// ATOMIC: split-K over blockIdx.z; epilogue unsafeAtomicAdd into C; bias added by z==0 only.
// LDS chunk (16B = 8 bf16): logical k-chunk c of row r stored at slot r*4 + (c ^ ((r>>1)&3)).
// XCD swizzle (m204 bijective): each XCD gets a contiguous chunk of the (x,y) grid -> A/B L2 reuse.
template<typename TC, bool RELU, bool RESID, bool ATOMIC>
__global__ __launch_bounds__(512) void mgemm_k(const u16* __restrict__ A, const u16* __restrict__ WT,
    const float* __restrict__ bias, const float* __restrict__ R, TC* __restrict__ C,
    int M, int N, int Kc, int lda, int ldb)
{
  __shared__ __align__(16) u16 sA[2][128 * 32];   // 16 KB
  __shared__ __align__(16) u16 sB[2][256 * 32];   // 32 KB
  int t = threadIdx.x;

  // bijective XCD-aware remap of the flattened (x,y) id
  int gx = gridDim.x;
  int nwg = gx * gridDim.y;
  int flat = blockIdx.y * gx + blockIdx.x;
  int q = nwg >> 3, rr = nwg & 7;
  int xcd = flat & 7, idx = flat >> 3;
  int swz = (xcd < rr ? xcd * (q + 1) : rr * (q + 1) + (xcd - rr) * q) + idx;
  int bx = swz % gx, by = swz / gx;

  int n0 = bx * 256, m0 = by * 128;
  int koff = blockIdx.z * Kc;
  int lane = t & 63, wave = t >> 6;
  int wm = (wave >> 2) * 64, wn = (wave & 3) * 64;
  int quad = lane >> 4, l15 = lane & 15;

  // staging: A = 1 issue (512 chunks), B = 2 issues (1024 chunks); chunk ch -> row ch>>2, slot ch&3
  int rA = t >> 2, sc = t & 3;
  int cA = sc ^ ((rA >> 1) & 3);
  int raA = m0 + rA; raA = raA < M ? raA : M - 1;
  const u16* gA  = A  + (size_t)raA * lda + koff + cA * 8;
  int rB = t >> 2;
  int cB = sc ^ ((rB >> 1) & 3);          // same for rB and rB+128 ((r+128)>>1 & 3 unchanged)
  const u16* gB0 = WT + (size_t)(n0 + rB) * ldb + koff + cB * 8;
  const u16* gB1 = WT + (size_t)(n0 + 128 + rB) * ldb + koff + cB * 8;
  u16* lA  = &sA[0][t * 8];
  u16* lB0 = &sB[0][t * 8];
  u16* lB1 = &sB[0][(512 + t) * 8];

  f32x4 acc[4][4];
  #pragma unroll
  for (int i = 0; i < 4; ++i)
    #pragma unroll
    for (int j = 0; j < 4; ++j) acc[i][j] = (f32x4){0.f, 0.f, 0.f, 0.f};

  const int nt = Kc >> 5;
  // prologue: stage tile 0 into buf 0
  gload16(gA, lA); gload16(gB0, lB0); gload16(gB1, lB1);
  int cur = 0;
  for (int tt = 0; tt < nt; ++tt) {
    __syncthreads();  // drains vmcnt(0): buf[cur] ready; prior reads of buf[cur^1] done
    if (tt + 1 < nt) {
      int k0 = (tt + 1) << 5;
      gload16(gA + k0, lA + (cur ^ 1) * 4096);
      gload16(gB0 + k0, lB0 + (cur ^ 1) * 8192);
      gload16(gB1 + k0, lB1 + (cur ^ 1) * 8192);
    }
    short8 af[4], bf[4];
    #pragma unroll
    for (int i = 0; i < 4; ++i) {
      int ra = wm + i * 16 + l15;
      af[i] = *(const short8*)&sA[cur][ra * 32 + (quad ^ ((ra >> 1) & 3)) * 8];
    }
    #pragma unroll
    for (int j = 0; j < 4; ++j) {
      int rb = wn + j * 16 + l15;
      bf[j] = *(const short8*)&sB[cur][rb * 32 + (quad ^ ((rb >> 1) & 3)) * 8];
    }
    #pragma unroll
    for (int i = 0; i < 4; ++i)
      #pragma unroll
      for (int j = 0; j < 4; ++j)
        acc[i][j] = __builtin_amdgcn_mfma_f32_16x16x32_bf16(af[i], bf[j], acc[i][j], 0, 0, 0);
    cur ^= 1;
  }

  // epilogue: D row = quad*4+reg (m), col = lane&15 (n)  [m89-verified]
  #pragma unroll
  for (int i = 0; i < 4; ++i) {
    int mBase = m0 + wm + i * 16 + quad * 4;
    #pragma unroll
    for (int r = 0; r < 4; ++r) {
      int m = mBase + r;
      if (m < M) {
        #pragma unroll
        for (int j = 0; j < 4; ++j) {
          int n = n0 + wn + j * 16 + l15;
          if constexpr (ATOMIC) {
            float v = acc[i][j][r];
            if (blockIdx.z == 0) v += bias[n];
            unsafeAtomicAdd(&((float*)C)[(size_t)m * N + n], v);
          } else {
            float v = acc[i][j][r] + bias[n];
            if (RESID) v += R[(size_t)m * N + n];
            if (RELU) v = fmaxf(v, 0.f);
            if constexpr (sizeof(TC) == 2) ((u16*)C)[(size_t)m * N + n] = f2b(v);
            else ((float*)C)[(size_t)m * N + n] = v;
          }
        }
      }
    }
  }
}

// ---------- in-place LayerNorm, also emits bf16 shadow ----------
__global__ __launch_bounds__(256) void ln_k(float* h, u16* __restrict__ hb,
    const float* __restrict__ g, const float* __restrict__ bb)
{
  __shared__ float rs[256], rq[256];
  float* p = h + (size_t)blockIdx.x * 512;
  u16* pb = hb + (size_t)blockIdx.x * 512;
  int t = threadIdx.x;
  float v0 = p[t], v1 = p[t + 256];
  rs[t] = v0 + v1; rq[t] = v0 * v0 + v1 * v1;
  __syncthreads();
  for (int o = 128; o > 0; o >>= 1) {
    if (t < o) { rs[t] += rs[t + o]; rq[t] += rq[t + o]; }
    __syncthreads();
  }
  float mean = rs[0] * (1.f / 512.f);
  float var = fmaxf(rq[0] * (1.f / 512.f) - mean * mean, 0.f);
  float rinv = rsqrtf(var + 1e-5f);
  float o0 = (v0 - mean) * rinv * g[t] + bb[t];
  float o1 = (v1 - mean) * rinv * g[t + 256] + bb[t + 256];
  p[t] = o0; p[t + 256] = o1;
  pb[t] = f2b(o0); pb[t + 256] = f2b(o1);
}

// ---------- sparse block attention, MFMA version: one wave per (b, h, n) ----------
__global__ __launch_bounds__(64) void attnm_k(const u16* __restrict__ qkv, u16* __restrict__ av,
    const int* __restrict__ rnd, int S, int Sp, int nb)
{
  __shared__ __align__(16) u16 Vt[64 * 104];
  __shared__ __align__(16) u16 Pl[16 * 104];
  __shared__ int sJB[10], sVD[10];
  int t = threadIdx.x;
  int n = blockIdx.x % nb;
  int r1 = blockIdx.x / nb;
  int hh = r1 & 7, b = r1 >> 3;
  const u16* base = qkv + (size_t)b * Sp * 1536;
  int l15 = t & 15, quad = t >> 4;

  if (t < 10) {
    int jb, vd;
    if (t < 2) { jb = t; vd = 1; }
    else if (t < 7) {
      int w = n + t - 4;
      vd = (w >= 0 && w < nb) ? 1 : 0;
      jb = w < 0 ? 0 : (w > nb - 1 ? nb - 1 : w);
    } else { jb = rnd[n * 3 + t - 7]; vd = 1; }
    sJB[t] = jb; sVD[t] = vd;
  }
  {
    f32x4 zz = {0.f, 0.f, 0.f, 0.f};
    *(f32x4*)&Vt[t * 104 + 80] = zz;
    *(f32x4*)&Vt[t * 104 + 88] = zz;
    if (t < 16) {
      *(f32x4*)&Pl[t * 104 + 80] = zz;
      *(f32x4*)&Pl[t * 104 + 88] = zz;
    }
  }
  __syncthreads();

  short8 aq0, aq1;
  {
    const u16* qp = base + (size_t)(n * 8 + (l15 & 7)) * 1536 + hh * 64 + quad * 8;
    aq0 = *(const short8*)qp;
    aq1 = *(const short8*)(qp + 32);
  }

  f32x4 s[5];
  float okm[5];
  #pragma unroll
  for (int tile = 0; tile < 5; ++tile) {
    int kb = tile * 2 + (l15 >> 3);
    int tok = sJB[kb] * 8 + (l15 & 7);
    okm[tile] = (sVD[kb] && tok < S) ? 0.f : -3.0e38f;
    const u16* kp = base + (size_t)tok * 1536 + 512 + hh * 64 + quad * 8;
    short8 k0 = *(const short8*)kp;
    short8 k1 = *(const short8*)(kp + 32);
    f32x4 c = {0.f, 0.f, 0.f, 0.f};
    c = __builtin_amdgcn_mfma_f32_16x16x32_bf16(aq0, k0, c, 0, 0, 0);
    c = __builtin_amdgcn_mfma_f32_16x16x32_bf16(aq1, k1, c, 0, 0, 0);
    s[tile] = c;
  }

  u16 vreg[80];
  #pragma unroll
  for (int vt = 0; vt < 10; ++vt) {
    const u16* vp = base + (size_t)(sJB[vt] * 8) * 1536 + 1024 + hh * 64 + t;
    #pragma unroll
    for (int j = 0; j < 8; ++j) vreg[vt * 8 + j] = vp[(size_t)j * 1536];
  }

  f32x4 mx = {-3.0e38f, -3.0e38f, -3.0e38f, -3.0e38f};
  #pragma unroll
  for (int tile = 0; tile < 5; ++tile) {
    #pragma unroll
    for (int r = 0; r < 4; ++r) {
      float v = s[tile][r] * 0.125f + okm[tile];
      s[tile][r] = v;
      mx[r] = fmaxf(mx[r], v);
    }
  }
  #pragma unroll
  for (int off = 1; off < 16; off <<= 1) {
    #pragma unroll
    for (int r = 0; r < 4; ++r) mx[r] = fmaxf(mx[r], __shfl_xor(mx[r], off));
  }
  f32x4 sm = {0.f, 0.f, 0.f, 0.f};
  #pragma unroll
  for (int tile = 0; tile < 5; ++tile) {
    #pragma unroll
    for (int r = 0; r < 4; ++r) {
      float e = __expf(s[tile][r] - mx[r]);
      s[tile][r] = e;
      sm[r] += e;
    }
  }
  #pragma unroll
  for (int off = 1; off < 16; off <<= 1) {
    #pragma unroll
    for (int r = 0; r < 4; ++r) sm[r] += __shfl_xor(sm[r], off);
  }

  #pragma unroll
  for (int tile = 0; tile < 5; ++tile)
    #pragma unroll
    for (int r = 0; r < 4; ++r)
      Pl[(quad * 4 + r) * 104 + tile * 16 + l15] = f2b(s[tile][r]);

  #pragma unroll
  for (int vt = 0; vt < 10; ++vt) {
    short8 w;
    #pragma unroll
    for (int j = 0; j < 8; ++j) ((u16*)&w)[j] = (short)vreg[vt * 8 + j];
    *(short8*)&Vt[t * 104 + vt * 8] = w;
  }
  __syncthreads();

  f32x4 o[4];
  #pragma unroll
  for (int dn = 0; dn < 4; ++dn) o[dn] = (f32x4){0.f, 0.f, 0.f, 0.f};
  #pragma unroll
  for (int ks = 0; ks < 3; ++ks) {
    short8 ap = *(const short8*)&Pl[l15 * 104 + ks * 32 + quad * 8];
    #pragma unroll
    for (int dn = 0; dn < 4; ++dn) {
      short8 bv = *(const short8*)&Vt[(dn * 16 + l15) * 104 + ks * 32 + quad * 8];
      o[dn] = __builtin_amdgcn_mfma_f32_16x16x32_bf16(ap, bv, o[dn], 0, 0, 0);
    }
  }

  if (quad < 2) {
    #pragma unroll
    for (int r = 0; r < 4; ++r) {
      int qi = quad * 4 + r;
      float inv = 1.f / sm[r];
      u16* op = av + ((size_t)b * Sp + n * 8 + qi) * 512 + hh * 64 + l15;
      #pragma unroll
      for (int dn = 0; dn < 4; ++dn)
        op[dn * 16] = f2b(o[dn][r] * inv);
    }
  }
}

// ---------- VAE head ----------
__global__ __launch_bounds__(512) void head_k(const float* __restrict__ h,
    const float* __restrict__ Wm, const float* __restrict__ bm,
    const float* __restrict__ Wlv, const float* __restrict__ blv,
    const float* __restrict__ eps, float* __restrict__ z, float* out_elbo)
{
  __shared__ float red[512];
  int t = threadIdx.x;
  int b = t >> 4, i = t & 15;
  const float* p = h + (size_t)b * SPENC * 512;
  float am = bm[i], al = blv[i];
  for (int c = 0; c < 512; ++c) {
    float pv = p[c];
    am += pv * Wm[c * 16 + i];
    al += pv * Wlv[c * 16 + i];
  }
  z[t] = am + eps[t] * expf(0.5f * al);
  red[t] = -0.5f * (1.f + al - am * am - expf(al));
  __syncthreads();
  for (int o = 256; o > 0; o >>= 1) { if (t < o) red[t] += red[t + o]; __syncthreads(); }
  if (t == 0) out_elbo[0] = red[0] * (1.f / 32.f);
}

// ---------- seq ----------
__global__ __launch_bounds__(256) void seq_k(const float* __restrict__ z, const float* __restrict__ We,
    const float* __restrict__ be, float* __restrict__ seq)
{
  int gid = blockIdx.x * 256 + threadIdx.x;
  int b = gid >> 11, c = gid & 2047;
  float acc = be[c];
  #pragma unroll
  for (int i = 0; i < 16; ++i) acc += z[b * 16 + i] * We[i * 2048 + c];
  seq[gid] = acc;
}

// ---------- decoder init: h fp32 + hb bf16 ----------
__global__ __launch_bounds__(256) void decinit_k(const float* __restrict__ seq, const float* __restrict__ Wc,
    const float* __restrict__ bc, const float* __restrict__ emb, float* __restrict__ h, u16* __restrict__ hb)
{
  size_t gid = (size_t)blockIdx.x * 256 + threadIdx.x;
  int dd = (int)(gid & 511);
  size_t rs = gid >> 9;
  int s = (int)(rs & 1023);
  int b = (int)(rs >> 10);
  float v = seq[b * 2048 + s] * Wc[dd] + seq[b * 2048 + 1024 + s] * Wc[512 + dd]
          + bc[dd] + emb[(size_t)s * 512 + dd];
  h[gid] = v;
  hb[gid] = f2b(v);
}

// ---------- final ----------
__global__ __launch_bounds__(256) void final_k(const float* __restrict__ h, const float* __restrict__ Ws,
    const float* __restrict__ bs, float* __restrict__ out)
{
  int gid = blockIdx.x * 256 + threadIdx.x;
  int nn = gid & 15;
  int rs = gid >> 4;
  const float* p = h + (size_t)rs * 512;
  float acc = bs[nn];
  for (int c = 0; c < 512; ++c) acc += p[c] * Ws[c * 16 + nn];
  out[gid] = acc;
}

extern "C" void kernel_launch(void* const* d_in, const int* in_sizes, int n_in,
                              void* d_out, int out_size, void* d_ws, size_t ws_size,
                              hipStream_t stream) {
  float* out = (float*)d_out;
  (void)out_size; (void)ws_size;

  static const int EXP_DICT[30] = {
    524288, 512, 524800, 524288, 8192, 512, 7864320, 15360, 2621440, 5120,
    5120, 5120, 10485760, 20480, 10485760, 5120, 5120, 5120, 8192, 16,
    8192, 16, 32768, 2048, 1024, 512, 8192, 16, 387, 384 };
  bool dict_ok = (n_in == 30);
  if (dict_ok) for (int i = 0; i < 30; ++i) if (in_sizes[i] != EXP_DICT[i]) { dict_ok = false; break; }
  if (!dict_ok) { beacon_k<<<1, 64, 0, stream>>>(out); return; }

  const float* x      = (const float*)d_in[0];
  const float* eps    = (const float*)d_in[1];
  const float* emb_in = (const float*)d_in[2];
  const float* emb_out= (const float*)d_in[3];
  const float* W_data = (const float*)d_in[4];
  const float* b_data = (const float*)d_in[5];
  const float* Wqkv   = (const float*)d_in[6];
  const float* bqkv   = (const float*)d_in[7];
  const float* Wo     = (const float*)d_in[8];
  const float* bo     = (const float*)d_in[9];
  const float* ln1g   = (const float*)d_in[10];
  const float* ln1b   = (const float*)d_in[11];
  const float* W1     = (const float*)d_in[12];
  const float* b1     = (const float*)d_in[13];
  const float* W2     = (const float*)d_in[14];
  const float* b2     = (const float*)d_in[15];
  const float* ln2g   = (const float*)d_in[16];
  const float* ln2b   = (const float*)d_in[17];
  const float* Wm     = (const float*)d_in[18];
  const float* bm     = (const float*)d_in[19];
  const float* Wlv    = (const float*)d_in[20];
  const float* blv    = (const float*)d_in[21];
  const float* Wexp   = (const float*)d_in[22];
  const float* bexp   = (const float*)d_in[23];
  const float* Wconv  = (const float*)d_in[24];
  const float* bconv  = (const float*)d_in[25];
  const float* Wseq   = (const float*)d_in[26];
  const float* bseq   = (const float*)d_in[27];
  const int* rand_enc = (const int*)d_in[28];
  const int* rand_dec = (const int*)d_in[29];

  // ---- workspace carve (~194.5 MB; proven-safe envelope 203 MB) ----
  char* ws = (char*)d_ws;
  float* h     = (float*)ws;
  u16*   hb    = (u16*)(ws + 67633152);
  u16*   WTqkv = (u16*)(ws + 101449728);
  u16*   WTo   = (u16*)(ws + 117178368);
  u16*   WT1l  = (u16*)(ws + 122421248);
  u16*   WT2l  = (u16*)(ws + 124518400);
  u16*   qkvb  = (u16*)(ws + 126615552);
  u16*   avb   = (u16*)(ws + 126615552 + 50724864);
  u16*   ffnb  = (u16*)(ws + 126615552);             // union with qkvb+avb
  float* seqb  = (float*)(ws + 194248704);
  float* z     = (float*)(ws + 194510848);

  // ---- persistent weight transpose+convert (qkv, o for all 10 layers) ----
  tr_k<<<dim3(512 / 32, 1536 / 32, 10), 256, 0, stream>>>(Wqkv, WTqkv, 512, 1536);
  tr_k<<<dim3(512 / 32, 512 / 32, 10), 256, 0, stream>>>(Wo, WTo, 512, 512);

  // ===== encoder: M=33024; attention path in 2 chunks of 16 batches (Mc=16512) =====
  {
    const int M = MENC;
    embed_k<<<(M * 512) / 256, 256, 0, stream>>>(x, W_data, b_data, emb_in, h, hb);
    for (int i = 0; i < 5; ++i) {
      for (int bc = 0; bc < 2; ++bc) {
        size_t roff = (size_t)bc * 16 * SPENC * 512;
        const int Mc = 16 * SPENC;  // 16512
        const int ty = 129;         // 16512/128
        mgemm_k<u16, false, false, false><<<dim3(1536 / 256, ty, 1), 512, 0, stream>>>(
            hb + roff, WTqkv + (size_t)i * 512 * 1536, bqkv + (size_t)i * 1536, nullptr, qkvb, Mc, 1536, 512, 512, 512);
        attnm_k<<<16 * 8 * NBE, 64, 0, stream>>>(qkvb, avb, rand_enc, SENC, SPENC, NBE);
        // Wo: split-K=2, atomic into h (h pre-holds residual)
        mgemm_k<float, false, false, true><<<dim3(512 / 256, ty, 2), 512, 0, stream>>>(
            avb, WTo + (size_t)i * 512 * 512, bo + (size_t)i * 512, nullptr, h + roff, Mc, 512, 256, 512, 512);
      }
      ln_k<<<M, 256, 0, stream>>>(h, hb, ln1g + (size_t)i * 512, ln1b + (size_t)i * 512);
      // per-layer FFN weight transposes (WT1l/WT2l)
      tr_k<<<dim3(512 / 32, 2048 / 32, 1), 256, 0, stream>>>(W1 + (size_t)i * 512 * 2048, WT1l, 512, 2048);
      tr_k<<<dim3(2048 / 32, 512 / 32, 1), 256, 0, stream>>>(W2 + (size_t)i * 2048 * 512, WT2l, 2048, 512);
      for (int off = 0; off < M; off += 16512) {
        const int Mc = 16512;  // 33024 = 2 * 16512 exactly
        const int ty = 129;
        mgemm_k<u16, true, false, false><<<dim3(2048 / 256, ty, 1), 512, 0, stream>>>(
            hb + (size_t)off * 512, WT1l, b1 + (size_t)i * 2048, nullptr, ffnb, Mc, 2048, 512, 512, 512);
        // W2: split-K=2 (Kc=1024), atomic into h (h pre-holds post-ln1 residual)
        mgemm_k<float, false, false, true><<<dim3(512 / 256, ty, 2), 512, 0, stream>>>(
            ffnb, WT2l, b2 + (size_t)i * 512, nullptr, h + (size_t)off * 512, Mc, 512, 1024, 2048, 2048);
      }
      ln_k<<<M, 256, 0, stream>>>(h, hb, ln2g + (size_t)i * 512, ln2b + (size_t)i * 512);
    }
  }

  // ===== VAE head =====
  head_k<<<1, 512, 0, stream>>>(h, Wm, bm, Wlv, blv, eps, z, out + 524288);
  seq_k<<<256, 256, 0, stream>>>(z, Wexp, bexp, seqb);
  decinit_k<<<(MDEC * 512) / 256, 256, 0, stream>>>(seqb, Wconv, bconv, emb_out, h, hb);

  // ===== decoder: M=32768; attention path in 2 chunks of 16 batches (Mc=16384) =====
  {
    const int M = MDEC;
    for (int i = 5; i < 10; ++i) {
      for (int bc = 0; bc < 2; ++bc) {
        size_t roff = (size_t)bc * 16 * SDEC * 512;
        const int Mc = 16 * SDEC;  // 16384
        const int ty = 128;
        mgemm_k<u16, false, false, false><<<dim3(1536 / 256, ty, 1), 512, 0, stream>>>(
            hb + roff, WTqkv + (size_t)i * 512 * 1536, bqkv + (size_t)i * 1536, nullptr, qkvb, Mc, 1536, 512, 512, 512);
        attnm_k<<<16 * 8 * NBD, 64, 0, stream>>>(qkvb, avb, rand_dec, SDEC, SDEC, NBD);
        mgemm_k<float, false, false, true><<<dim3(512 / 256, ty, 2), 512, 0, stream>>>(
            avb, WTo + (size_t)i * 512 * 512, bo + (size_t)i * 512, nullptr, h + roff, Mc, 512, 256, 512, 512);
      }
      ln_k<<<M, 256, 0, stream>>>(h, hb, ln1g + (size_t)i * 512, ln1b + (size_t)i * 512);
      tr_k<<<dim3(512 / 32, 2048 / 32, 1), 256, 0, stream>>>(W1 + (size_t)i * 512 * 2048, WT1l, 512, 2048);
      tr_k<<<dim3(2048 / 32, 512 / 32, 1), 256, 0, stream>>>(W2 + (size_t)i * 2048 * 512, WT2l, 2048, 512);
      for (int off = 0; off < M; off += 16384) {
        const int Mc = 16384;
        const int ty = 128;
        mgemm_k<u16, true, false, false><<<dim3(2048 / 256, ty, 1), 512, 0, stream>>>(
            hb + (size_t)off * 512, WT1l, b1 + (size_t)i * 2048, nullptr, ffnb, Mc, 2048, 512, 512, 512);
        mgemm_k<float, false, false, true><<<dim3(512 / 256, ty, 2), 512, 0, stream>>>(
            ffnb, WT2l, b2 + (size_t)i * 512, nullptr, h + (size_t)off * 512, Mc, 512, 1024, 2048, 2048);
      }
      ln_k<<<M, 256, 0, stream>>>(h, hb, ln2g + (size_t)i * 512, ln2b + (size_t)i * 512);
    }
  }

  // ===== output =====
  final_k<<<524288 / 256, 256, 0, stream>>>(h, Wseq, bseq, out);
}